// Round 12
// baseline (383.055 us; speedup 1.0000x reference)
//
#include <hip/hip_runtime.h>

typedef __bf16 bf16;
typedef __attribute__((ext_vector_type(8))) __bf16 bf16x8;
typedef __attribute__((ext_vector_type(2))) __bf16 bf16x2;
typedef __attribute__((ext_vector_type(4))) float f32x4;
typedef __attribute__((ext_vector_type(16))) float f32x16;
typedef __attribute__((ext_vector_type(8))) unsigned short ushort8;   // 16B
typedef __attribute__((ext_vector_type(4))) unsigned short ushort4v;  // 8B

__device__ __forceinline__ unsigned short f2bf(float f) {
    union { float f; unsigned int u; } v; v.f = f;
    unsigned int u = v.u;
    return (unsigned short)((u + 0x7fffu + ((u >> 16) & 1u)) >> 16);
}

#if __has_builtin(__builtin_amdgcn_cvt_pk_bf16_f32)
__device__ __forceinline__ unsigned int pk2bf(float a, float b) {
    union { bf16x2 v; unsigned int u; } c;
    c.v = __builtin_amdgcn_cvt_pk_bf16_f32(a, b);
    return c.u;
}
#else
__device__ __forceinline__ unsigned int pk2bf(float a, float b) {
    return (unsigned int)f2bf(a) | ((unsigned int)f2bf(b) << 16);
}
#endif

__device__ __forceinline__ f32x4 mfma16(bf16x8 a, bf16x8 b, f32x4 c) {
    return __builtin_amdgcn_mfma_f32_16x16x32_bf16(a, b, c, 0, 0, 0);
}
__device__ __forceinline__ f32x16 mfma32(bf16x8 a, bf16x8 b, f32x16 c) {
    return __builtin_amdgcn_mfma_f32_32x32x16_bf16(a, b, c, 0, 0, 0);
}

// async global->LDS 16B: HW places lane i's data at ldsbase + i*16 (wave-uniform base).
#if __has_builtin(__builtin_amdgcn_global_load_lds)
__device__ __forceinline__ void gload16(const unsigned short* g, unsigned short* l) {
    typedef const unsigned int __attribute__((address_space(1)))* gp_t;
    typedef unsigned int __attribute__((address_space(3)))* lp_t;
    __builtin_amdgcn_global_load_lds((gp_t)(const void*)g, (lp_t)(void*)l, 16, 0, 0);
}
#define GLL_LANE 1
#else
#define GLL_LANE 0
#endif

// ---------------- fused fp32 -> bf16 convert ----------------
__global__ void cvt3_f32_bf16(const float* __restrict__ x, const float* __restrict__ wq,
                              const float* __restrict__ wp,
                              unsigned short* __restrict__ xb, unsigned short* __restrict__ wqb,
                              unsigned short* __restrict__ wpb) {
    int i = blockIdx.x * 256 + threadIdx.x;   // float4 index
    const float* in; unsigned short* out; int base;
    if (i < 1572864)      { in = x;  out = xb;  base = i; }
    else if (i < 2015232) { in = wq; out = wqb; base = i - 1572864; }
    else if (i < 2162688) { in = wp; out = wpb; base = i - 2015232; }
    else return;
    float4 f = reinterpret_cast<const float4*>(in)[base];
    union { ushort4v v; unsigned int u[2]; } o;
    o.u[0] = pk2bf(f.x, f.y);
    o.u[1] = pk2bf(f.z, f.w);
    reinterpret_cast<ushort4v*>(out)[base] = o.v;
}

// key permutation for 32x32 S^T C-layout -> PV A-layout:  p: a -> bits (a0,a1,a3,a4,a2)
__device__ __forceinline__ int kperm(int k5) {
    return (k5 & 3) | (((k5 >> 3) & 1) << 2) | (((k5 >> 4) & 1) << 3) | (((k5 >> 2) & 1) << 4);
}
__device__ __forceinline__ int kperm_inv(int p5) {
    return (p5 & 3) | (((p5 >> 4) & 1) << 2) | (((p5 >> 2) & 1) << 3) | (((p5 >> 3) & 1) << 4);
}

// ---------------- QKV GEMM -> fragment-ready chunked layouts (unchanged from R11) ----------------
__global__ __launch_bounds__(256) void qkv_gemm(const unsigned short* __restrict__ A,
                                                const unsigned short* __restrict__ W,
                                                unsigned short* __restrict__ Qf,
                                                unsigned short* __restrict__ Kf,
                                                unsigned short* __restrict__ Vf) {
    __shared__ __align__(16) char smem[34816];
    unsigned short* As = (unsigned short*)smem;            // 128x32 (8 KB)
    unsigned short* Bs = (unsigned short*)(smem + 8192);   // 128x32 (8 KB)
    unsigned short* T  = (unsigned short*)smem;            // epilogue tile 128x136
    const int t = threadIdx.x;
    const int w = t >> 6, l = t & 63;
    const int wm = (w >> 1) * 64, wn = (w & 1) * 64;
    const int lr = l & 15, lq = l >> 4;
    const int m0 = blockIdx.y * 128, n0 = blockIdx.x * 128;
    f32x4 acc[4][4] = {};
    for (int k0 = 0; k0 < 768; k0 += 32) {
        __syncthreads();
#pragma unroll
        for (int i = 0; i < 2; ++i) {
            int v = t + i * 256;
            int r = v >> 2, c8 = (v & 3) * 8;
#if GLL_LANE
            gload16(&A[(m0 + r) * 768 + k0 + c8], &As[(w * 64 + i * 256) * 8]);
            gload16(&W[(n0 + r) * 768 + k0 + c8], &Bs[(w * 64 + i * 256) * 8]);
#else
            *reinterpret_cast<ushort8*>(&As[r * 32 + c8]) =
                *reinterpret_cast<const ushort8*>(&A[(m0 + r) * 768 + k0 + c8]);
            *reinterpret_cast<ushort8*>(&Bs[r * 32 + c8]) =
                *reinterpret_cast<const ushort8*>(&W[(n0 + r) * 768 + k0 + c8]);
#endif
        }
        __syncthreads();
        bf16x8 af[4], bfr[4];
#pragma unroll
        for (int mt = 0; mt < 4; ++mt)
            af[mt] = *reinterpret_cast<const bf16x8*>(&As[(wm + mt * 16 + lr) * 32 + lq * 8]);
#pragma unroll
        for (int nt = 0; nt < 4; ++nt)
            bfr[nt] = *reinterpret_cast<const bf16x8*>(&Bs[(wn + nt * 16 + lr) * 32 + lq * 8]);
#pragma unroll
        for (int mt = 0; mt < 4; ++mt)
#pragma unroll
            for (int nt = 0; nt < 4; ++nt)
                acc[mt][nt] = mfma16(af[mt], bfr[nt], acc[mt][nt]);
    }
    // ---- epilogue: C tile -> LDS (V region transposed) -> coalesced b128 stores ----
    const int tsel = n0 / 768;
    __syncthreads();
    if (tsel < 2) {
#pragma unroll
        for (int nt = 0; nt < 4; ++nt)
#pragma unroll
            for (int mt = 0; mt < 4; ++mt)
#pragma unroll
                for (int r = 0; r < 4; ++r) {
                    int row = wm + mt * 16 + lq * 4 + r;
                    int col = wn + nt * 16 + lr;
                    float val = acc[mt][nt][r];
                    if (tsel == 0) val *= 0.14724444f;   // SCALE*log2e
                    T[row * 136 + col] = f2bf(val);
                }
    } else {
#pragma unroll
        for (int nt = 0; nt < 4; ++nt)
#pragma unroll
            for (int mt = 0; mt < 4; ++mt)
#pragma unroll
                for (int r = 0; r < 4; ++r) {
                    int row = wm + mt * 16 + lq * 4 + r;   // key token
                    int col = wn + nt * 16 + lr;           // feature
                    T[col * 136 + row] = f2bf(acc[mt][nt][r]);  // transposed
                }
    }
    __syncthreads();
    if (tsel < 2) {
#pragma unroll
        for (int i = 0; i < 8; ++i) {
            int idx = t + i * 256;
            int pos31 = idx & 31;
            int rest = idx >> 5;
            int c8 = rest & 15, qg = rest >> 4;
            int l31 = (tsel == 1) ? kperm_inv(pos31) : pos31;
            int gncol = n0 + c8 * 8;
            int rem = gncol - tsel * 768;
            int head = rem / 96, d = rem - head * 96;
            int kq = d >> 4, h2 = (d >> 3) & 1;
            int gm = m0 + qg * 32 + l31;
            int b = gm >> 12, nn = gm & 4095;
            int bh = b * 8 + head;
            long chunk = (long)(bh * 128 + (nn >> 5)) * 6 + kq;
            ushort8 v8 = *reinterpret_cast<const ushort8*>(&T[(qg * 32 + l31) * 136 + c8 * 8]);
            unsigned short* dst = (tsel == 0) ? Qf : Kf;
            *reinterpret_cast<ushort8*>(&dst[(chunk << 9) + ((h2 * 32 + pos31) << 3)]) = v8;
        }
    } else {
#pragma unroll
        for (int i = 0; i < 8; ++i) {
            int idx = t + i * 256;
            int dl = idx & 31;
            int rr = idx >> 5;
            int r8 = rr & 15, cmb = rr >> 4;
            int col = cmb * 32 + dl;
            int gncol = n0 + col;
            int rem = gncol - 1536;
            int head = rem / 96, d = rem - head * 96;
            int dn = d >> 5;
            int keybase = m0 + r8 * 8;
            int b = keybase >> 12, nn = keybase & 4095;
            int kg = nn >> 5, f = (nn >> 4) & 1, hv = (nn >> 3) & 1;
            int bh = b * 8 + head;
            long chunk = (long)(bh * 128 + kg) * 6 + dn * 2 + f;
            ushort8 v8 = *reinterpret_cast<const ushort8*>(&T[col * 136 + r8 * 8]);
            *reinterpret_cast<ushort8*>(&Vf[(chunk << 9) + ((hv * 32 + dl) << 3)]) = v8;
        }
    }
}

// ---------------- Flash attention: Q-frags in LDS (frees 48 VGPR), unroll-2 pipelined ----------------
// 256 thr = 4 waves (wr: q half, wk: kv half). Loop reads aq via ds_read_b128 (idle DS pipe);
// freed registers let the scheduler hoist next-iter K/V global loads (barrier-free loop).
__global__ __launch_bounds__(256, 2) void attn_kernel(const unsigned short* __restrict__ Qf,
                                                      const unsigned short* __restrict__ Kf,
                                                      const unsigned short* __restrict__ Vf,
                                                      unsigned short* __restrict__ Og) {
    __shared__ __align__(16) char lds[24576];
    unsigned short* Qs = (unsigned short*)lds;   // 24 chunks x 1KB (loop)
    float*          red = (float*)lds;           // 128x36 epilogue reduce (aliased, post-loop)
    const int t = threadIdx.x;
    const int w = t >> 6, l = t & 63;
    const int wr = w >> 1, wk = w & 1;
    const int l31 = l & 31, h = l >> 5;
    const int b0 = blockIdx.x;
    const int kk = b0 >> 3;
    const int bh = (b0 & 7) * 2 + (kk >> 5);
    const int qg0 = (kk & 31) * 4;     // first q-group (of 32 rows) for this block
    const int q0 = qg0 * 32;
    const int voff = l << 3;           // lane's ushort offset within a chunk

    // stage this block's 24 Q-chunks (linear in Qf) into LDS
    {
        const long qfb = ((long)((bh * 128 + qg0) * 6)) << 9;
#pragma unroll
        for (int j = 0; j < 6; ++j) {
            int idx = t + j * 256;
            *reinterpret_cast<ushort8*>(&Qs[idx * 8]) =
                *reinterpret_cast<const ushort8*>(&Qf[qfb + idx * 8]);
        }
    }
    __syncthreads();
    const int aqb0 = ((wr * 2 + 0) * 6) << 9;   // ushort offset of qn=0 chunk row
    const int aqb1 = ((wr * 2 + 1) * 6) << 9;

    bf16x8 ones8;
#pragma unroll
    for (int i = 0; i < 8; ++i) ones8[i] = (__bf16)1.0f;

    f32x16 acc[2][3] = {};   // [qn][dn]
    f32x16 acc_l[2] = {};

#pragma unroll 2
    for (int it = 0; it < 64; ++it) {
        const int kt = wk * 64 + it;
        const long kbase = ((long)((bh * 128 + kt) * 6)) << 9;
        // S^T = K_perm Q^T (32x32x16); aq from LDS each iter
        f32x16 s[2] = {};
#pragma unroll
        for (int kq = 0; kq < 6; ++kq) {
            bf16x8 bk = *reinterpret_cast<const bf16x8*>(&Kf[kbase + (kq << 9) + voff]);
            bf16x8 a0 = *reinterpret_cast<const bf16x8*>(&Qs[aqb0 + (kq << 9) + voff]);
            bf16x8 a1 = *reinterpret_cast<const bf16x8*>(&Qs[aqb1 + (kq << 9) + voff]);
            s[0] = mfma32(bk, a0, s[0]);
            s[1] = mfma32(bk, a1, s[1]);
        }
        // p = exp2(s); C-reg -> PV A-frag slot map: frag f slot j <- reg (j&3)+8*((j>>2)&1)+4*f
        union PF { unsigned int u[4]; bf16x8 v8; } p[2][2];
#pragma unroll
        for (int qn = 0; qn < 2; ++qn) {
            float e[16];
#pragma unroll
            for (int r = 0; r < 16; ++r) e[r] = __builtin_amdgcn_exp2f(s[qn][r]);
#pragma unroll
            for (int f = 0; f < 2; ++f) {
                p[qn][f].u[0] = pk2bf(e[4 * f + 0], e[4 * f + 1]);
                p[qn][f].u[1] = pk2bf(e[4 * f + 2], e[4 * f + 3]);
                p[qn][f].u[2] = pk2bf(e[8 + 4 * f + 0], e[8 + 4 * f + 1]);
                p[qn][f].u[3] = pk2bf(e[8 + 4 * f + 2], e[8 + 4 * f + 3]);
            }
        }
        // O += P V (32x32x16), V fragments straight from L2
#pragma unroll
        for (int dn = 0; dn < 3; ++dn) {
#pragma unroll
            for (int f = 0; f < 2; ++f) {
                bf16x8 vb = *reinterpret_cast<const bf16x8*>(
                    &Vf[kbase + ((dn * 2 + f) << 9) + voff]);
                acc[0][dn] = mfma32(p[0][f].v8, vb, acc[0][dn]);
                acc[1][dn] = mfma32(p[1][f].v8, vb, acc[1][dn]);
            }
        }
#pragma unroll
        for (int qn = 0; qn < 2; ++qn)
#pragma unroll
            for (int f = 0; f < 2; ++f)
                acc_l[qn] = mfma32(p[qn][f].v8, ones8, acc_l[qn]);
    }

    // ---- cross-wave reduce over wk (pairs, stride 36 floats); Qs dead, red aliases LDS ----
    const int rbase = (wr * 64 + l) * 36;
#pragma unroll
    for (int ps = 0; ps < 3; ++ps) {
        __syncthreads();
        if (wk == 1) {
#pragma unroll
            for (int c = 0; c < 2; ++c) {
                int c2 = ps * 2 + c, qn = c2 / 3, dn = c2 % 3;
#pragma unroll
                for (int u = 0; u < 4; ++u) {
                    f32x4 tmp;
#pragma unroll
                    for (int j = 0; j < 4; ++j) tmp[j] = acc[qn][dn][u * 4 + j];
                    *reinterpret_cast<f32x4*>(&red[rbase + c * 16 + u * 4]) = tmp;
                }
            }
        }
        __syncthreads();
        if (wk == 0) {
#pragma unroll
            for (int c = 0; c < 2; ++c) {
                int c2 = ps * 2 + c, qn = c2 / 3, dn = c2 % 3;
#pragma unroll
                for (int u = 0; u < 4; ++u) {
                    f32x4 tmp = *reinterpret_cast<const f32x4*>(&red[rbase + c * 16 + u * 4]);
#pragma unroll
                    for (int j = 0; j < 4; ++j) acc[qn][dn][u * 4 + j] += tmp[j];
                }
            }
        }
    }
    __syncthreads();
    if (wk == 1) {
#pragma unroll
        for (int qn = 0; qn < 2; ++qn)
#pragma unroll
            for (int u = 0; u < 4; ++u) {
                f32x4 tmp;
#pragma unroll
                for (int j = 0; j < 4; ++j) tmp[j] = acc_l[qn][u * 4 + j];
                *reinterpret_cast<f32x4*>(&red[rbase + qn * 16 + u * 4]) = tmp;
            }
    }
    __syncthreads();
    if (wk == 0) {
#pragma unroll
        for (int qn = 0; qn < 2; ++qn)
#pragma unroll
            for (int u = 0; u < 4; ++u) {
                f32x4 tmp = *reinterpret_cast<const f32x4*>(&red[rbase + qn * 16 + u * 4]);
#pragma unroll
                for (int j = 0; j < 4; ++j) acc_l[qn][u * 4 + j] += tmp[j];
            }
        const int b = bh >> 3, head = bh & 7;
#pragma unroll
        for (int qn = 0; qn < 2; ++qn) {
#pragma unroll
            for (int reg = 0; reg < 16; ++reg) {
                int qloc = (reg & 3) + 8 * (reg >> 2) + 4 * h;
                int n = q0 + wr * 64 + qn * 32 + qloc;
                float inv = 1.f / acc_l[qn][reg];
                int rowoff = (b * 4096 + n) * 768 + head * 96;
#pragma unroll
                for (int dn = 0; dn < 3; ++dn)
                    Og[rowoff + dn * 32 + l31] = f2bf(acc[qn][dn][reg] * inv);
            }
        }
    }
}

// ---------------- proj GEMM: 128x64 tiles (grid 12x64 = 768 blocks = 3/CU) ----------------
__global__ __launch_bounds__(256) void proj_gemm(const unsigned short* __restrict__ A,
                                                 const unsigned short* __restrict__ W,
                                                 float* __restrict__ out) {
    __shared__ __align__(16) unsigned short As[128 * 32];
    __shared__ __align__(16) unsigned short Bs[64 * 32];
    const int t = threadIdx.x;
    const int w = t >> 6, l = t & 63;
    const int wm = (w >> 1) * 64, wn = (w & 1) * 32;
    const int lr = l & 15, lq = l >> 4;
    const int m0 = blockIdx.y * 128, n0 = blockIdx.x * 64;
    f32x4 acc[4][2] = {};
    for (int k0 = 0; k0 < 768; k0 += 32) {
        __syncthreads();
        {
            int v = t, r = v >> 2, c8 = (v & 3) * 8;
            int v2 = t + 256, r2 = v2 >> 2, c82 = (v2 & 3) * 8;
#if GLL_LANE
            gload16(&A[(m0 + r) * 768 + k0 + c8], &As[(w * 64) * 8]);
            gload16(&A[(m0 + r2) * 768 + k0 + c82], &As[(w * 64 + 256) * 8]);
            gload16(&W[(n0 + r) * 768 + k0 + c8], &Bs[(w * 64) * 8]);
#else
            *reinterpret_cast<ushort8*>(&As[r * 32 + c8]) =
                *reinterpret_cast<const ushort8*>(&A[(m0 + r) * 768 + k0 + c8]);
            *reinterpret_cast<ushort8*>(&As[r2 * 32 + c82]) =
                *reinterpret_cast<const ushort8*>(&A[(m0 + r2) * 768 + k0 + c82]);
            *reinterpret_cast<ushort8*>(&Bs[r * 32 + c8]) =
                *reinterpret_cast<const ushort8*>(&W[(n0 + r) * 768 + k0 + c8]);
#endif
        }
        __syncthreads();
        bf16x8 af[4], bfr[2];
#pragma unroll
        for (int mt = 0; mt < 4; ++mt)
            af[mt] = *reinterpret_cast<const bf16x8*>(&As[(wm + mt * 16 + lr) * 32 + lq * 8]);
#pragma unroll
        for (int nt = 0; nt < 2; ++nt)
            bfr[nt] = *reinterpret_cast<const bf16x8*>(&Bs[(wn + nt * 16 + lr) * 32 + lq * 8]);
#pragma unroll
        for (int mt = 0; mt < 4; ++mt)
#pragma unroll
            for (int nt = 0; nt < 2; ++nt)
                acc[mt][nt] = mfma16(af[mt], bfr[nt], acc[mt][nt]);
    }
#pragma unroll
    for (int nt = 0; nt < 2; ++nt) {
        int gn = n0 + wn + nt * 16 + lr;
#pragma unroll
        for (int mt = 0; mt < 4; ++mt) {
#pragma unroll
            for (int r = 0; r < 4; ++r) {
                int gm = m0 + wm + mt * 16 + lq * 4 + r;
                out[gm * 768 + gn] = acc[mt][nt][r];
            }
        }
    }
}

extern "C" void kernel_launch(void* const* d_in, const int* in_sizes, int n_in,
                              void* d_out, int out_size, void* d_ws, size_t ws_size,
                              hipStream_t stream) {
    const float* x     = (const float*)d_in[0];   // [2,4096,768] fp32
    const float* wqkv  = (const float*)d_in[1];   // [2304,768] fp32
    const float* wproj = (const float*)d_in[2];   // [768,768] fp32
    float* out = (float*)d_out;                   // fp32 [2,4096,768]
    char* ws = (char*)d_ws;
    unsigned short* xb     = (unsigned short*)(ws);             // 12582912
    unsigned short* wqkvb  = (unsigned short*)(ws + 12582912);  // 3538944
    unsigned short* wprojb = (unsigned short*)(ws + 16121856);  // 1179648
    unsigned short* Qf     = (unsigned short*)(ws + 17301504);  // frag chunks
    unsigned short* Kf     = (unsigned short*)(ws + 29884416);  // frag chunks
    unsigned short* Vf     = (unsigned short*)(ws + 42467328);  // frag chunks
    unsigned short* attnb  = xb;                                // reuse: [B,N,C] bf16

    cvt3_f32_bf16<<<8448, 256, 0, stream>>>(x, wqkv, wproj, xb, wqkvb, wprojb);
    qkv_gemm<<<dim3(18, 64), 256, 0, stream>>>(xb, wqkvb, Qf, Kf, Vf);
    attn_kernel<<<512, 256, 0, stream>>>(Qf, Kf, Vf, attnb);
    proj_gemm<<<dim3(12, 64), 256, 0, stream>>>(attnb, wprojb, out);
}